// Round 8
// baseline (234.322 us; speedup 1.0000x reference)
//
#include <hip/hip_runtime.h>
#include <hip/hip_bf16.h>

// EdgeConv B=8,C=64,N=4096,OUT=64,K=20.
// h[b,o,n,k] = z[b,n,o] - y[b,idx_k,o];  out = leakyrelu((z - min/max_k y)*inv + bias)
#define NN 4096
#define KK 20
#define LL 12        // per-thread sorted list of GROUP keys (group = 4 consecutive m)
#define KP 196       // keysL row pitch in dwords (192 keys + 4 pad)
#define EXTRG 24     // groups merged out before rescore (exact: bearing groups are top-<=20)
#define NF 24        // fp64-rescored finalists

typedef short bf16x8 __attribute__((ext_vector_type(8)));
typedef float f32x4  __attribute__((ext_vector_type(4)));

__device__ __forceinline__ unsigned umax_(unsigned a, unsigned b){ return a > b ? a : b; }
__device__ __forceinline__ unsigned umin_(unsigned a, unsigned b){ return a < b ? a : b; }

__device__ __forceinline__ unsigned bfbits(float f) {   // fp32 -> bf16 bits, RNE
    unsigned u = __float_as_uint(f);
    return (u + 0x7FFFu + ((u >> 16) & 1u)) >> 16;
}
__device__ __forceinline__ float bflo(unsigned u){ return __builtin_bit_cast(float, u << 16); }
__device__ __forceinline__ float bfhi(unsigned u){ return __builtin_bit_cast(float, u & 0xFFFF0000u); }

__device__ __forceinline__ uint4 packfrag_u(float4 lo, float4 hi) {
    return make_uint4(bfbits(lo.x) | (bfbits(lo.y) << 16),
                      bfbits(lo.z) | (bfbits(lo.w) << 16),
                      bfbits(hi.x) | (bfbits(hi.y) << 16),
                      bfbits(hi.z) | (bfbits(hi.w) << 16));
}

// ---- DPP cross-lane (row = 16 lanes; row_ror:n = 0x120+n) -------------------
template<int CTRL>
__device__ __forceinline__ int dpp_mov(int v) {
    return __builtin_amdgcn_update_dpp(0, v, CTRL, 0xF, 0xF, true);
}
template<int CTRL>
__device__ __forceinline__ float dpp_addf(float v) {
    return v + __builtin_bit_cast(float, dpp_mov<CTRL>(__builtin_bit_cast(int, v)));
}
template<int CTRL>
__device__ __forceinline__ unsigned dpp_maxu(unsigned v) {
    return umax_(v, (unsigned)dpp_mov<CTRL>((int)v));
}
__device__ __forceinline__ float rowsum16(float v) {
    v = dpp_addf<0x128>(v); v = dpp_addf<0x124>(v);
    v = dpp_addf<0x122>(v); v = dpp_addf<0x121>(v);
    return v;
}
__device__ __forceinline__ unsigned rowmax16(unsigned v) {
    v = dpp_maxu<0x128>(v); v = dpp_maxu<0x124>(v);
    v = dpp_maxu<0x122>(v); v = dpp_maxu<0x121>(v);
    return v;
}

// ---------------- Kernel 1 (fused prep): transpose + xx + bf16 + y/z MFMA ----------------
// 512 blocks x 512 threads (8 waves) = 2 blocks/CU, 16 waves/CU.
__global__ __launch_bounds__(512) void k_prep(
    const float* __restrict__ x, const float* __restrict__ W,
    float* __restrict__ xt, unsigned short* __restrict__ xbf,
    unsigned short* __restrict__ ybf, unsigned short* __restrict__ zbf,
    double* __restrict__ xxd, float* __restrict__ xxc)
{
    __shared__ __align__(16) float fS[64 * 65];   // fp32 transpose staging (pitch 65)
    __shared__ __align__(16) uint4 bS[64 * 9];    // bf16 rows (pitch 9 uint4)
    __shared__ __align__(16) uint4 WfS[1024];     // 16384 B W fragments
    __shared__ double dS[8 * 64];                 // fp64 partials
    int tid = threadIdx.x;
    int b   = blockIdx.x >> 6;
    int n0  = (blockIdx.x & 63) << 6;
    int r   = tid & 63, p = tid >> 6;             // p in 0..7 -> 8 channels each
    size_t brow = (size_t)b * NN;
    int n = n0 + r;

    {   // W fragments (x-independent) -> LDS; layout (o*16 + sel*4 + quad)
        const float4* W4 = (const float4*)W;      // W row = 32 float4
        #pragma unroll
        for (int i = 0; i < 2; ++i) {
            int idx = i*512 + tid;                // 0..1023
            int o = idx >> 4, sel = (idx >> 2) & 3, quad = idx & 3;
            float4 lo = W4[(size_t)o*32 + sel*8 + quad*2];
            float4 hi = W4[(size_t)o*32 + sel*8 + quad*2 + 1];
            WfS[idx] = packfrag_u(lo, hi);
        }
    }

    float v[8];
    double s = 0.0;
    #pragma unroll
    for (int i = 0; i < 8; ++i) {
        float t = x[((size_t)(b*64 + p*8 + i) << 12) + n];   // 256B coalesced across r
        v[i] = t;
        s += (double)t * (double)t;
    }
    dS[p*64 + r] = s;
    #pragma unroll
    for (int i = 0; i < 8; ++i) fS[r*65 + p*8 + i] = v[i];
    {
        unsigned pk[4];
        #pragma unroll
        for (int i = 0; i < 4; ++i)
            pk[i] = bfbits(v[2*i]) | (bfbits(v[2*i+1]) << 16);
        bS[r*9 + p] = make_uint4(pk[0], pk[1], pk[2], pk[3]);
    }
    __syncthreads();      // only barrier: fS/bS/WfS/dS all ready, read-only after

    if (tid < 64) {
        double xx = 0.0;
        #pragma unroll
        for (int q = 0; q < 8; ++q) xx += dS[q*64 + tid];
        xxd[brow + n0 + tid] = xx;
        // HALF-bias: Gram seeds MFMA C with this directly (score = old/2, exact
        // monotone); stage-3 rescore uses p + xxc == old sc/2 bit-exact. (R6-verified)
        xxc[brow + n0 + tid] = (1024.f - (float)xx) * 0.5f;
    }
    // coalesced fp32 xt store: 1024 float4, 2 per thread
    #pragma unroll
    for (int i = 0; i < 2; ++i) {
        int idx = i*512 + tid;                 // 0..1023
        int rr = idx >> 4, c4 = idx & 15;
        float4 o = make_float4(fS[rr*65 + 4*c4],     fS[rr*65 + 4*c4 + 1],
                               fS[rr*65 + 4*c4 + 2], fS[rr*65 + 4*c4 + 3]);
        *(float4*)(xt + (brow + n0 + rr)*64 + 4*c4) = o;
    }
    // coalesced bf16 store: 512 uint4, 1 per thread
    {
        int rr = tid >> 3, u = tid & 7;
        ((uint4*)xbf)[(brow + n0 + rr)*8 + u] = bS[rr*9 + u];
    }

    // ---- y/z MFMA: 8 waves; wave w -> row-tile (w&3), ot-half (w>>2) ----
    int w = tid >> 6, lane = tid & 63, quad = lane >> 4, c = lane & 15;
    int lrow = (w & 3)*16 + c;
    bf16x8 bb0 = __builtin_bit_cast(bf16x8, bS[lrow*9 + quad]);       // ch quad*8..+7
    bf16x8 bb1 = __builtin_bit_cast(bf16x8, bS[lrow*9 + 4 + quad]);   // ch 32+quad*8..+7
    int nw = n0 + lrow;
    #pragma unroll 1
    for (int oh = 0; oh < 2; ++oh) {
        int ot = (w >> 2)*2 + oh;
        const uint4* wf = WfS + (ot*16 + c)*16 + quad;
        bf16x8 w1a = __builtin_bit_cast(bf16x8, wf[0]);
        bf16x8 w1b = __builtin_bit_cast(bf16x8, wf[4]);
        bf16x8 w2a = __builtin_bit_cast(bf16x8, wf[8]);
        bf16x8 w2b = __builtin_bit_cast(bf16x8, wf[12]);
        f32x4 acc1 = __builtin_amdgcn_mfma_f32_16x16x32_bf16(
            w1a, bb0, (f32x4){0.f,0.f,0.f,0.f}, 0, 0, 0);
        acc1 = __builtin_amdgcn_mfma_f32_16x16x32_bf16(w1b, bb1, acc1, 0, 0, 0);
        f32x4 acc2 = __builtin_amdgcn_mfma_f32_16x16x32_bf16(
            w2a, bb0, (f32x4){0.f,0.f,0.f,0.f}, 0, 0, 0);
        acc2 = __builtin_amdgcn_mfma_f32_16x16x32_bf16(w2b, bb1, acc2, 0, 0, 0);
        // thread (quad,c): o = ot*16 + quad*4 + j, n = nw; y=acc1, z=acc1+acc2
        float z0 = acc1[0]+acc2[0], z1 = acc1[1]+acc2[1],
              z2 = acc1[2]+acc2[2], z3 = acc1[3]+acc2[3];
        size_t obase = (brow + nw) * 64 + (ot*16 + quad*4);
        *(uint2*)(ybf + obase) = make_uint2(
            bfbits(acc1[0]) | (bfbits(acc1[1]) << 16),
            bfbits(acc1[2]) | (bfbits(acc1[3]) << 16));
        *(uint2*)(zbf + obase) = make_uint2(
            bfbits(z0) | (bfbits(z1) << 16),
            bfbits(z2) | (bfbits(z3) << 16));
    }
}

// ---------------- Kernel 2 (fused): 32-n tile Gram + top-12 keys + refine ----------------
// R7 body with ONE change: A-stream prefetch depth 2 -> 4 (Gram chunk time ~120 cyc
// barely covers L2 latency at depth 2; depth 4 adds slack). Extra state ~24 VGPR on
// top of 56; grid caps residency at 4 waves/SIMD so <=128 VGPR is free. Refine is
// R7-verbatim (R6's lambda/interleave rewrite -- the suspected spill source -- omitted).
// Spill tripwire: WRITE_SIZE must stay ~8192 KB.
__global__ __launch_bounds__(256, 4) void k_main(
    const unsigned short* __restrict__ xbf, const float* __restrict__ xt,
    const double* __restrict__ xxd, const float* __restrict__ xxc,
    const unsigned short* __restrict__ ybf, const unsigned short* __restrict__ zbf,
    const float* __restrict__ gamma, const float* __restrict__ beta,
    const float* __restrict__ rmean, const float* __restrict__ rvar,
    float* __restrict__ out)
{
    __shared__ __align__(16) unsigned keysL[32 * KP];     // 25088 B (dead after pass 1)
    __shared__ __align__(16) unsigned gselS[32 * EXTRG];  // 3 KB
    // pass-2 scratch aliased into dead keysL (dword offsets; 5056 <= 6272 used):
    float*  outS = (float*)keysL;              // [0,2112)    64 o x pitch 33
    double* d26S = (double*)(keysL + 2112);    // [2112,3648) 32*NF doubles (byte 8448, 16B-aligned)
    int*    m26S = (int*)   (keysL + 3648);    // [3648,4416) 32*NF
    int*    selS = (int*)   (keysL + 4416);    // [4416,5056) 32*KK

    int tid  = threadIdx.x;
    int w    = tid >> 6, lane = tid & 63;
    int quad = lane >> 4, c = lane & 15;
    int b  = blockIdx.x & 7;                 // batch <-> XCD affinity
    int n0 = (blockIdx.x >> 3) << 5;         // 32-n tile
    size_t brow = (size_t)b * NN;

    const uint4* xb = (const uint4*)xbf;     // one row = 8 uint4

    // B fragments for the two fixed n-tiles
    size_t nr0 = (brow + n0 + c) * 8 + quad;
    size_t nr1 = (brow + n0 + 16 + c) * 8 + quad;
    bf16x8 b00 = __builtin_bit_cast(bf16x8, xb[nr0]);
    bf16x8 b01 = __builtin_bit_cast(bf16x8, xb[nr0 + 4]);
    bf16x8 b10 = __builtin_bit_cast(bf16x8, xb[nr1]);
    bf16x8 b11 = __builtin_bit_cast(bf16x8, xb[nr1 + 4]);

    unsigned kA[LL], kB[LL];
    #pragma unroll
    for (int i = 0; i < LL; ++i) { kA[i] = 0u; kB[i] = 0u; }

    // A stream, prefetch depth 4
    size_t abase = (brow + 16*w + c) * 8 + quad;
    size_t xxb   = brow + 16*w + quad*4;
    uint4  a0p[4], a1p[4];
    float4 xxp[4];
    #pragma unroll
    for (int i = 0; i < 4; ++i) {
        a0p[i] = xb[abase + (size_t)i*512];
        a1p[i] = xb[abase + (size_t)i*512 + 4];
        xxp[i] = *(const float4*)(xxc + xxb + i*64);
    }

    #pragma unroll 4
    for (int chunk = 0; chunk < 64; ++chunk) {
        int s = chunk & 3;                   // constant after unroll-4
        uint4 ca0 = a0p[s], ca1 = a1p[s];
        f32x4 cin = __builtin_bit_cast(f32x4, xxp[s]);   // C-init = (1024-xx_m)/2
        if (chunk < 60) {
            size_t nb = abase + (size_t)(chunk + 4) * 512;
            a0p[s] = xb[nb]; a1p[s] = xb[nb + 4];
            xxp[s] = *(const float4*)(xxc + xxb + (chunk + 4)*64);
        }
        // acc = x_m . x_n + (1024 - xx_m)/2  ==  (old score)/2, monotone
        f32x4 accA = __builtin_amdgcn_mfma_f32_16x16x32_bf16(
            __builtin_bit_cast(bf16x8, ca0), b00, cin, 0, 0, 0);
        accA = __builtin_amdgcn_mfma_f32_16x16x32_bf16(
            __builtin_bit_cast(bf16x8, ca1), b01, accA, 0, 0, 0);
        f32x4 accB = __builtin_amdgcn_mfma_f32_16x16x32_bf16(
            __builtin_bit_cast(bf16x8, ca0), b10, cin, 0, 0, 0);
        accB = __builtin_amdgcn_mfma_f32_16x16x32_bf16(
            __builtin_bit_cast(bf16x8, ca1), b11, accB, 0, 0, 0);

        unsigned gid = (unsigned)((chunk << 4) | (w << 2) | quad);
        {   // tile 0: n = n0+c
            float gm = fmaxf(fmaxf(accA[0], accA[1]), fmaxf(accA[2], accA[3]));
            unsigned key = (__float_as_uint(gm) & 0xFFFFFC00u) | gid;
            #pragma unroll
            for (int t = 0; t < LL; ++t) {
                unsigned mx = umax_(kA[t], key);
                key = umin_(kA[t], key);
                kA[t] = mx;
            }
        }
        {   // tile 1: n = n0+16+c  (independent CE chain - interleaves with tile 0)
            float gm = fmaxf(fmaxf(accB[0], accB[1]), fmaxf(accB[2], accB[3]));
            unsigned key = (__float_as_uint(gm) & 0xFFFFFC00u) | gid;
            #pragma unroll
            for (int t = 0; t < LL; ++t) {
                unsigned mx = umax_(kB[t], key);
                key = umin_(kB[t], key);
                kB[t] = mx;
            }
        }
    }

    // park lists: row = 16*tile + c, list id = 4w+quad
    {
        uint4* kd0 = (uint4*)(keysL + c*KP + (w*4 + quad)*LL);
        kd0[0] = make_uint4(kA[0], kA[1], kA[2],  kA[3]);
        kd0[1] = make_uint4(kA[4], kA[5], kA[6],  kA[7]);
        kd0[2] = make_uint4(kA[8], kA[9], kA[10], kA[11]);
        uint4* kd1 = (uint4*)(keysL + (16 + c)*KP + (w*4 + quad)*LL);
        kd1[0] = make_uint4(kB[0], kB[1], kB[2],  kB[3]);
        kd1[1] = make_uint4(kB[4], kB[5], kB[6],  kB[7]);
        kd1[2] = make_uint4(kB[8], kB[9], kB[10], kB[11]);
    }
    __syncthreads();

    // ================= refine (quarter-wave per row; 2 rows per thread-group) ========
    int r = tid >> 4, g = tid & 15;

    // pass 1: stage 1+2 for both rows -> gselS; after this keysL is dead
    #pragma unroll 1
    for (int rr = 0; rr < 2; ++rr) {
        int row = rr*16 + r;
        unsigned mk[LL];
        {
            const uint4* ks = (const uint4*)(keysL + row*KP + g*LL);
            uint4 k0 = ks[0], k1 = ks[1], k2 = ks[2];
            mk[0]=k0.x; mk[1]=k0.y; mk[2]=k0.z;  mk[3]=k0.w;
            mk[4]=k1.x; mk[5]=k1.y; mk[6]=k1.z;  mk[7]=k1.w;
            mk[8]=k2.x; mk[9]=k2.y; mk[10]=k2.z; mk[11]=k2.w;
        }
        #pragma unroll 1
        for (int it = 0; it < EXTRG; ++it) {
            unsigned vm = rowmax16(mk[0]);
            bool win = (mk[0] == vm);
            #pragma unroll
            for (int q = 0; q < LL-1; ++q) mk[q] = win ? mk[q+1] : mk[q];
            mk[LL-1] = win ? 0u : mk[LL-1];
            if (g == (it & 15)) gselS[row*EXTRG + it] = vm;
        }
    }
    __syncthreads();   // keysL reads done -> aliased scratch may now be written

    // pass 2: stages 3..6 per row
    #pragma unroll 1
    for (int rr = 0; rr < 2; ++rr) {
        int row = rr*16 + r;
        int n = n0 + row;
        uint2 anb = *(const uint2*)(xbf + (brow + n) * 64 + 4*g);
        float an0 = bflo(anb.x), an1 = bfhi(anb.x),
              an2 = bflo(anb.y), an3 = bfhi(anb.y);

        // stage 3: bf16 cooperative rescore of 96 candidates
        unsigned myk[6];
        #pragma unroll
        for (int j = 0; j < 6; ++j) {
            uint4 Gj = *(const uint4*)(gselS + row*EXTRG + 4*j);
            unsigned gk4[4] = {Gj.x, Gj.y, Gj.z, Gj.w};
            #pragma unroll
            for (int h = 0; h < 2; ++h) {
                uint2 vbs[8]; float xxm[8];
                #pragma unroll
                for (int u = 0; u < 8; ++u) {
                    int t = h*8 + u;
                    int m = (int)((gk4[t >> 2] & 1023u) << 2) | (t & 3);
                    vbs[u] = *(const uint2*)(xbf + (brow + m) * 64 + 4*g);
                    xxm[u] = xxc[brow + m];
                }
                #pragma unroll
                for (int u = 0; u < 8; ++u) {
                    int t = h*8 + u;
                    float p = an0 * bflo(vbs[u].x);
                    p = fmaf(an1, bfhi(vbs[u].x), p);
                    p = fmaf(an2, bflo(vbs[u].y), p);
                    p = fmaf(an3, bfhi(vbs[u].y), p);
                    p = rowsum16(p);
                    float sc = p + xxm[u];   // xxc is half-bias: == old sc/2 bit-exact
                    unsigned key = (__float_as_uint(sc) & 0xFFFFFF80u) | (unsigned)(j*16 + t);
                    if (t == g) myk[j] = key;
                }
            }
        }
        #pragma unroll
        for (int a = 1; a < 6; ++a)
            #pragma unroll
            for (int q = a; q > 0; --q) {
                unsigned lo = umin_(myk[q-1], myk[q]);
                myk[q-1] = umax_(myk[q-1], myk[q]);
                myk[q] = lo;
            }

        // stage 3.5: pop-shift merge -> exact top-NF of the 96 fp32 keys
        #pragma unroll 1
        for (int it = 0; it < NF; ++it) {
            unsigned vm = rowmax16(myk[0]);
            bool win = (myk[0] == vm);
            #pragma unroll
            for (int q = 0; q < 5; ++q) myk[q] = win ? myk[q+1] : myk[q];
            myk[5] = win ? 0u : myk[5];
            if (g == (it & 15)) {
                int i = (int)(vm & 127u);
                unsigned gk = gselS[row*EXTRG + (i >> 2)];
                m26S[row*NF + it] = (int)((gk & 1023u) << 2) | (i & 3);
            }
        }

        // stage 4: fp64 per-lane full dots (lane = candidate)
        #pragma unroll
        for (int round = 0; round < 2; ++round) {
            int t = round*16 + g;
            if (t < NF) {
                int m = m26S[row*NF + t];
                const float4* xm = (const float4*)(xt + (brow + m) * 64);
                const float4* xn = (const float4*)(xt + (brow + n) * 64);
                double acc0 = 0.0, acc1 = 0.0;
                #pragma unroll
                for (int i = 0; i < 8; ++i) {
                    float4 v0 = xm[2*i], a0 = xn[2*i];
                    float4 v1 = xm[2*i+1], a1 = xn[2*i+1];
                    acc0 += (double)a0.x*(double)v0.x + (double)a0.y*(double)v0.y
                          + (double)a0.z*(double)v0.z + (double)a0.w*(double)v0.w;
                    acc1 += (double)a1.x*(double)v1.x + (double)a1.y*(double)v1.y
                          + (double)a1.z*(double)v1.z + (double)a1.w*(double)v1.w;
                }
                d26S[row*NF + t] = 2.0*(acc0 + acc1) - xxd[brow + m];
            }
        }

        // stage 5: exact top-20 set by rank counting
        #pragma unroll
        for (int round = 0; round < 2; ++round) {
            int t = round*16 + g;
            if (t < NF) {
                double st = d26S[row*NF + t];
                int cnt = 0;
                #pragma unroll
                for (int p = 0; p < NF; ++p) cnt += (d26S[row*NF + p] > st) ? 1 : 0;
                if (cnt < KK) selS[row*KK + cnt] = m26S[row*NF + t];
            }
        }

        // stage 6: gather y (bf16), min/max per o, epilogue -> outS (aliased)
        float mn[4] = { __builtin_inff(), __builtin_inff(), __builtin_inff(), __builtin_inff() };
        float mx[4] = { -__builtin_inff(), -__builtin_inff(), -__builtin_inff(), -__builtin_inff() };
        #pragma unroll
        for (int hb = 0; hb < 2; ++hb) {
            uint2 yb[10];
            #pragma unroll
            for (int k = 0; k < 10; ++k)
                yb[k] = *(const uint2*)(ybf + (brow + selS[row*KK + hb*10 + k]) * 64 + 4*g);
            #pragma unroll
            for (int k = 0; k < 10; ++k) {
                float y0 = bflo(yb[k].x), y1 = bfhi(yb[k].x),
                      y2 = bflo(yb[k].y), y3 = bfhi(yb[k].y);
                mn[0] = fminf(mn[0], y0); mx[0] = fmaxf(mx[0], y0);
                mn[1] = fminf(mn[1], y1); mx[1] = fmaxf(mx[1], y1);
                mn[2] = fminf(mn[2], y2); mx[2] = fmaxf(mx[2], y2);
                mn[3] = fminf(mn[3], y3); mx[3] = fmaxf(mx[3], y3);
            }
        }
        uint2 zb = *(const uint2*)(zbf + (brow + n) * 64 + 4*g);
        float zz[4] = {bflo(zb.x), bfhi(zb.x), bflo(zb.y), bfhi(zb.y)};
        #pragma unroll
        for (int j = 0; j < 4; ++j) {
            int o = 4*g + j;
            float inv  = gamma[o] / sqrtf(rvar[o] + 1e-5f);
            float bias = beta[o] - rmean[o] * inv;
            float ysel = (inv >= 0.f) ? mn[j] : mx[j];
            float h = (zz[j] - ysel) * inv + bias;
            outS[o*33 + row] = (h >= 0.f) ? h : 0.2f * h;
        }
    }
    __syncthreads();   // cross-wave: output transpose
    {
        int o = tid >> 2, q = tid & 3;
        float* ob = outS + o*33;
        float4 v0 = make_float4(ob[4*q],      ob[4*q + 1],  ob[4*q + 2],  ob[4*q + 3]);
        float4 v1 = make_float4(ob[16 + 4*q], ob[17 + 4*q], ob[18 + 4*q], ob[19 + 4*q]);
        float* op = out + ((size_t)(b*64 + o) << 12) + n0;
        *(float4*)(op + 4*q)      = v0;
        *(float4*)(op + 16 + 4*q) = v1;
    }
}

extern "C" void kernel_launch(void* const* d_in, const int* in_sizes, int n_in,
                              void* d_out, int out_size, void* d_ws, size_t ws_size,
                              hipStream_t stream) {
    const float* x     = (const float*)d_in[0];
    const float* W     = (const float*)d_in[1];
    const float* gamma = (const float*)d_in[2];
    const float* beta  = (const float*)d_in[3];
    const float* rmean = (const float*)d_in[4];
    const float* rvar  = (const float*)d_in[5];
    float* out = (float*)d_out;

    char* ws = (char*)d_ws;
    float*          xt  = (float*)          (ws);                          //  8 MB
    unsigned short* xbf = (unsigned short*) (ws + ((size_t) 8 << 20));     //  4 MB
    unsigned short* ybf = (unsigned short*) (ws + ((size_t)12 << 20));     //  4 MB
    unsigned short* zbf = (unsigned short*) (ws + ((size_t)16 << 20));     //  4 MB
    double*         xxd = (double*)         (ws + ((size_t)20 << 20));     // 256 KB
    float*          xxc = (float*)          (ws + ((size_t)20 << 20) + (512 << 10)); // 128 KB

    k_prep<<< 512, 512, 0, stream>>>(x, W, xt, xbf, ybf, zbf, xxd, xxc);
    k_main<<<1024, 256, 0, stream>>>(xbf, xt, xxd, xxc, ybf, zbf,
                                     gamma, beta, rmean, rvar, out);
}

// Round 9
// 229.137 us; speedup vs baseline: 1.0226x; 1.0226x over previous
//
#include <hip/hip_runtime.h>
#include <hip/hip_bf16.h>

// EdgeConv B=8,C=64,N=4096,OUT=64,K=20.
// h[b,o,n,k] = z[b,n,o] - y[b,idx_k,o];  out = leakyrelu((z - min/max_k y)*inv + bias)
#define NN 4096
#define KK 20
#define LL 12        // per-thread sorted list of GROUP keys (group = 4 consecutive m)
#define KP 196       // keysL row pitch in dwords (192 keys + 4 pad)
#define EXTRG 24     // groups merged out before rescore (exact: bearing groups are top-<=20)
#define NF 24        // fp64-rescored finalists

typedef short bf16x8 __attribute__((ext_vector_type(8)));
typedef float f32x4  __attribute__((ext_vector_type(4)));

__device__ __forceinline__ unsigned umax_(unsigned a, unsigned b){ return a > b ? a : b; }
__device__ __forceinline__ unsigned umin_(unsigned a, unsigned b){ return a < b ? a : b; }

__device__ __forceinline__ unsigned bfbits(float f) {   // fp32 -> bf16 bits, RNE
    unsigned u = __float_as_uint(f);
    return (u + 0x7FFFu + ((u >> 16) & 1u)) >> 16;
}
__device__ __forceinline__ float bflo(unsigned u){ return __builtin_bit_cast(float, u << 16); }
__device__ __forceinline__ float bfhi(unsigned u){ return __builtin_bit_cast(float, u & 0xFFFF0000u); }

__device__ __forceinline__ uint4 packfrag_u(float4 lo, float4 hi) {
    return make_uint4(bfbits(lo.x) | (bfbits(lo.y) << 16),
                      bfbits(lo.z) | (bfbits(lo.w) << 16),
                      bfbits(hi.x) | (bfbits(hi.y) << 16),
                      bfbits(hi.z) | (bfbits(hi.w) << 16));
}

// ---- DPP cross-lane (row = 16 lanes; row_ror:n = 0x120+n) -------------------
template<int CTRL>
__device__ __forceinline__ int dpp_mov(int v) {
    return __builtin_amdgcn_update_dpp(0, v, CTRL, 0xF, 0xF, true);
}
template<int CTRL>
__device__ __forceinline__ float dpp_addf(float v) {
    return v + __builtin_bit_cast(float, dpp_mov<CTRL>(__builtin_bit_cast(int, v)));
}
template<int CTRL>
__device__ __forceinline__ unsigned dpp_maxu(unsigned v) {
    return umax_(v, (unsigned)dpp_mov<CTRL>((int)v));
}
__device__ __forceinline__ float rowsum16(float v) {
    v = dpp_addf<0x128>(v); v = dpp_addf<0x124>(v);
    v = dpp_addf<0x122>(v); v = dpp_addf<0x121>(v);
    return v;
}
__device__ __forceinline__ unsigned rowmax16(unsigned v) {
    v = dpp_maxu<0x128>(v); v = dpp_maxu<0x124>(v);
    v = dpp_maxu<0x122>(v); v = dpp_maxu<0x121>(v);
    return v;
}

// Exact top-12 of (a[12] desc-sorted) U (slot[12] desc-sorted), written back to slot.
// Batcher: half-cleaner of (a ++ rev(b)) padded to 16, then 16-elem bitonic sort (desc).
// All keys distinct positive uints -> result bit-identical to a single-stream top-12.
__device__ __forceinline__ void merge_top12(const unsigned (&a)[LL], unsigned* slot) {
    const uint4* ks = (const uint4*)slot;
    uint4 p0 = ks[0], p1 = ks[1], p2 = ks[2];
    unsigned pb[LL] = {p0.x,p0.y,p0.z,p0.w, p1.x,p1.y,p1.z,p1.w, p2.x,p2.y,p2.z,p2.w};
    unsigned m[16];
    m[0] = a[0]; m[1] = a[1]; m[2] = a[2]; m[3] = a[3];      // b_pad[15-i]=0
    #pragma unroll
    for (int i = 4; i < 12; ++i) m[i] = umax_(a[i], pb[15 - i]);
    m[12] = pb[3]; m[13] = pb[2]; m[14] = pb[1]; m[15] = pb[0];  // a_pad=0
#define CSW(i,j) { unsigned hi_ = umax_(m[i], m[j]), lo_ = umin_(m[i], m[j]); m[i] = hi_; m[j] = lo_; }
    CSW(0,8)  CSW(1,9)  CSW(2,10) CSW(3,11) CSW(4,12) CSW(5,13) CSW(6,14) CSW(7,15)
    CSW(0,4)  CSW(1,5)  CSW(2,6)  CSW(3,7)  CSW(8,12) CSW(9,13) CSW(10,14) CSW(11,15)
    CSW(0,2)  CSW(1,3)  CSW(4,6)  CSW(5,7)  CSW(8,10) CSW(9,11) CSW(12,14) CSW(13,15)
    CSW(0,1)  CSW(2,3)  CSW(4,5)  CSW(6,7)  CSW(8,9)  CSW(10,11) CSW(12,13) CSW(14,15)
#undef CSW
    uint4* kd = (uint4*)slot;
    kd[0] = make_uint4(m[0], m[1], m[2],  m[3]);
    kd[1] = make_uint4(m[4], m[5], m[6],  m[7]);
    kd[2] = make_uint4(m[8], m[9], m[10], m[11]);
}

// ---------------- Kernel 1 (fused prep): transpose + xx + bf16 + y/z MFMA ----------------
// 512 blocks x 512 threads (8 waves) = 2 blocks/CU, 16 waves/CU.
__global__ __launch_bounds__(512) void k_prep(
    const float* __restrict__ x, const float* __restrict__ W,
    float* __restrict__ xt, unsigned short* __restrict__ xbf,
    unsigned short* __restrict__ ybf, unsigned short* __restrict__ zbf,
    double* __restrict__ xxd, float* __restrict__ xxc)
{
    __shared__ __align__(16) float fS[64 * 65];   // fp32 transpose staging (pitch 65)
    __shared__ __align__(16) uint4 bS[64 * 9];    // bf16 rows (pitch 9 uint4)
    __shared__ __align__(16) uint4 WfS[1024];     // 16384 B W fragments
    __shared__ double dS[8 * 64];                 // fp64 partials
    int tid = threadIdx.x;
    int b   = blockIdx.x >> 6;
    int n0  = (blockIdx.x & 63) << 6;
    int r   = tid & 63, p = tid >> 6;             // p in 0..7 -> 8 channels each
    size_t brow = (size_t)b * NN;
    int n = n0 + r;

    {   // W fragments (x-independent) -> LDS; layout (o*16 + sel*4 + quad)
        const float4* W4 = (const float4*)W;      // W row = 32 float4
        #pragma unroll
        for (int i = 0; i < 2; ++i) {
            int idx = i*512 + tid;                // 0..1023
            int o = idx >> 4, sel = (idx >> 2) & 3, quad = idx & 3;
            float4 lo = W4[(size_t)o*32 + sel*8 + quad*2];
            float4 hi = W4[(size_t)o*32 + sel*8 + quad*2 + 1];
            WfS[idx] = packfrag_u(lo, hi);
        }
    }

    float v[8];
    double s = 0.0;
    #pragma unroll
    for (int i = 0; i < 8; ++i) {
        float t = x[((size_t)(b*64 + p*8 + i) << 12) + n];   // 256B coalesced across r
        v[i] = t;
        s += (double)t * (double)t;
    }
    dS[p*64 + r] = s;
    #pragma unroll
    for (int i = 0; i < 8; ++i) fS[r*65 + p*8 + i] = v[i];
    {
        unsigned pk[4];
        #pragma unroll
        for (int i = 0; i < 4; ++i)
            pk[i] = bfbits(v[2*i]) | (bfbits(v[2*i+1]) << 16);
        bS[r*9 + p] = make_uint4(pk[0], pk[1], pk[2], pk[3]);
    }
    __syncthreads();      // only barrier: fS/bS/WfS/dS all ready, read-only after

    if (tid < 64) {
        double xx = 0.0;
        #pragma unroll
        for (int q = 0; q < 8; ++q) xx += dS[q*64 + tid];
        xxd[brow + n0 + tid] = xx;
        // HALF-bias: Gram seeds MFMA C with this directly (score = old/2, exact
        // monotone); stage-3 rescore uses p + xxc == old sc/2 bit-exact. (R6-verified)
        xxc[brow + n0 + tid] = (1024.f - (float)xx) * 0.5f;
    }
    // coalesced fp32 xt store: 1024 float4, 2 per thread
    #pragma unroll
    for (int i = 0; i < 2; ++i) {
        int idx = i*512 + tid;                 // 0..1023
        int rr = idx >> 4, c4 = idx & 15;
        float4 o = make_float4(fS[rr*65 + 4*c4],     fS[rr*65 + 4*c4 + 1],
                               fS[rr*65 + 4*c4 + 2], fS[rr*65 + 4*c4 + 3]);
        *(float4*)(xt + (brow + n0 + rr)*64 + 4*c4) = o;
    }
    // coalesced bf16 store: 512 uint4, 1 per thread
    {
        int rr = tid >> 3, u = tid & 7;
        ((uint4*)xbf)[(brow + n0 + rr)*8 + u] = bS[rr*9 + u];
    }

    // ---- y/z MFMA: 8 waves; wave w -> row-tile (w&3), ot-half (w>>2) ----
    int w = tid >> 6, lane = tid & 63, quad = lane >> 4, c = lane & 15;
    int lrow = (w & 3)*16 + c;
    bf16x8 bb0 = __builtin_bit_cast(bf16x8, bS[lrow*9 + quad]);       // ch quad*8..+7
    bf16x8 bb1 = __builtin_bit_cast(bf16x8, bS[lrow*9 + 4 + quad]);   // ch 32+quad*8..+7
    int nw = n0 + lrow;
    #pragma unroll 1
    for (int oh = 0; oh < 2; ++oh) {
        int ot = (w >> 2)*2 + oh;
        const uint4* wf = WfS + (ot*16 + c)*16 + quad;
        bf16x8 w1a = __builtin_bit_cast(bf16x8, wf[0]);
        bf16x8 w1b = __builtin_bit_cast(bf16x8, wf[4]);
        bf16x8 w2a = __builtin_bit_cast(bf16x8, wf[8]);
        bf16x8 w2b = __builtin_bit_cast(bf16x8, wf[12]);
        f32x4 acc1 = __builtin_amdgcn_mfma_f32_16x16x32_bf16(
            w1a, bb0, (f32x4){0.f,0.f,0.f,0.f}, 0, 0, 0);
        acc1 = __builtin_amdgcn_mfma_f32_16x16x32_bf16(w1b, bb1, acc1, 0, 0, 0);
        f32x4 acc2 = __builtin_amdgcn_mfma_f32_16x16x32_bf16(
            w2a, bb0, (f32x4){0.f,0.f,0.f,0.f}, 0, 0, 0);
        acc2 = __builtin_amdgcn_mfma_f32_16x16x32_bf16(w2b, bb1, acc2, 0, 0, 0);
        // thread (quad,c): o = ot*16 + quad*4 + j, n = nw; y=acc1, z=acc1+acc2
        float z0 = acc1[0]+acc2[0], z1 = acc1[1]+acc2[1],
              z2 = acc1[2]+acc2[2], z3 = acc1[3]+acc2[3];
        size_t obase = (brow + nw) * 64 + (ot*16 + quad*4);
        *(uint2*)(ybf + obase) = make_uint2(
            bfbits(acc1[0]) | (bfbits(acc1[1]) << 16),
            bfbits(acc1[2]) | (bfbits(acc1[3]) << 16));
        *(uint2*)(zbf + obase) = make_uint2(
            bfbits(z0) | (bfbits(z1) << 16),
            bfbits(z2) | (bfbits(z3) << 16));
    }
}

// ---------------- Kernel 2 (fused): 32-n tile Gram + top-12 keys + refine ----------------
// 1024 blocks x 512 threads (8 waves). Chunk-half split: waves 0-3 = chunks 0-31,
// waves 4-7 = chunks 32-63, SAME two chains per wave (R7 structure). Half-lists are
// merged to the exact top-12 of the union (Batcher half-cleaner + bitonic-16) ->
// bit-identical lists/selection vs R7. Refine: all 32 rows in one pass (R5-verified).
// Per-wave state unchanged from R7 (56 VGPR); bounds (512,4) = R5's verified no-spill
// config; VGPR<=64 lets HW co-schedule 4 blocks/CU = 8 waves/SIMD (2x R7's overlap).
__global__ __launch_bounds__(512, 4) void k_main(
    const unsigned short* __restrict__ xbf, const float* __restrict__ xt,
    const double* __restrict__ xxd, const float* __restrict__ xxc,
    const unsigned short* __restrict__ ybf, const unsigned short* __restrict__ zbf,
    const float* __restrict__ gamma, const float* __restrict__ beta,
    const float* __restrict__ rmean, const float* __restrict__ rvar,
    float* __restrict__ out)
{
    __shared__ __align__(16) unsigned keysL[32 * KP];     // 25088 B (dead after pass 1)
    __shared__ __align__(16) unsigned gselS[32 * EXTRG];  // 3 KB
    // pass-2 scratch aliased into dead keysL (dword offsets; 5056 <= 6272 used):
    float*  outS = (float*)keysL;              // [0,2112)    64 o x pitch 33
    double* d26S = (double*)(keysL + 2112);    // [2112,3648) 32*NF doubles (byte 8448, 16B-aligned)
    int*    m26S = (int*)   (keysL + 3648);    // [3648,4416) 32*NF
    int*    selS = (int*)   (keysL + 4416);    // [4416,5056) 32*KK

    int tid  = threadIdx.x;
    int w    = tid >> 6, lane = tid & 63;
    int quad = lane >> 4, c = lane & 15;
    int wsub = w & 3, half = w >> 2;         // list-quartet x chunk-half
    int cb   = half << 5;                    // chunk base: 0 or 32
    int b  = blockIdx.x & 7;                 // batch <-> XCD affinity
    int n0 = (blockIdx.x >> 3) << 5;         // 32-n tile
    size_t brow = (size_t)b * NN;

    const uint4* xb = (const uint4*)xbf;     // one row = 8 uint4

    // B fragments for the two fixed n-tiles
    size_t nr0 = (brow + n0 + c) * 8 + quad;
    size_t nr1 = (brow + n0 + 16 + c) * 8 + quad;
    bf16x8 b00 = __builtin_bit_cast(bf16x8, xb[nr0]);
    bf16x8 b01 = __builtin_bit_cast(bf16x8, xb[nr0 + 4]);
    bf16x8 b10 = __builtin_bit_cast(bf16x8, xb[nr1]);
    bf16x8 b11 = __builtin_bit_cast(bf16x8, xb[nr1 + 4]);

    unsigned kA[LL], kB[LL];
    #pragma unroll
    for (int i = 0; i < LL; ++i) { kA[i] = 0u; kB[i] = 0u; }

    // A stream (this wave's 32-chunk half), prefetch depth 2
    size_t abase = (brow + 16*wsub + c) * 8 + quad;
    size_t xxb   = brow + 16*wsub + quad*4;
    uint4  a0p[2], a1p[2];
    float4 xxp[2];
    a0p[0] = xb[abase + (size_t)cb*512];       a1p[0] = xb[abase + (size_t)cb*512 + 4];
    a0p[1] = xb[abase + (size_t)(cb+1)*512];   a1p[1] = xb[abase + (size_t)(cb+1)*512 + 4];
    xxp[0] = *(const float4*)(xxc + xxb + cb*64);
    xxp[1] = *(const float4*)(xxc + xxb + (cb+1)*64);

    #pragma unroll 2
    for (int chunk = 0; chunk < 32; ++chunk) {
        int s = chunk & 1;                   // constant after unroll-2
        uint4 ca0 = a0p[s], ca1 = a1p[s];
        f32x4 cin = __builtin_bit_cast(f32x4, xxp[s]);   // C-init = (1024-xx_m)/2
        if (chunk < 30) {
            size_t nb = abase + (size_t)(cb + chunk + 2) * 512;
            a0p[s] = xb[nb]; a1p[s] = xb[nb + 4];
            xxp[s] = *(const float4*)(xxc + xxb + (cb + chunk + 2)*64);
        }
        // acc = x_m . x_n + (1024 - xx_m)/2  ==  (old score)/2, monotone
        f32x4 accA = __builtin_amdgcn_mfma_f32_16x16x32_bf16(
            __builtin_bit_cast(bf16x8, ca0), b00, cin, 0, 0, 0);
        accA = __builtin_amdgcn_mfma_f32_16x16x32_bf16(
            __builtin_bit_cast(bf16x8, ca1), b01, accA, 0, 0, 0);
        f32x4 accB = __builtin_amdgcn_mfma_f32_16x16x32_bf16(
            __builtin_bit_cast(bf16x8, ca0), b10, cin, 0, 0, 0);
        accB = __builtin_amdgcn_mfma_f32_16x16x32_bf16(
            __builtin_bit_cast(bf16x8, ca1), b11, accB, 0, 0, 0);

        unsigned gid = (unsigned)(((cb + chunk) << 4) | (wsub << 2) | quad);
        {   // tile 0: n = n0+c
            float gm = fmaxf(fmaxf(accA[0], accA[1]), fmaxf(accA[2], accA[3]));
            unsigned key = (__float_as_uint(gm) & 0xFFFFFC00u) | gid;
            #pragma unroll
            for (int t = 0; t < LL; ++t) {
                unsigned mx = umax_(kA[t], key);
                key = umin_(kA[t], key);
                kA[t] = mx;
            }
        }
        {   // tile 1: n = n0+16+c  (independent CE chain - interleaves with tile 0)
            float gm = fmaxf(fmaxf(accB[0], accB[1]), fmaxf(accB[2], accB[3]));
            unsigned key = (__float_as_uint(gm) & 0xFFFFFC00u) | gid;
            #pragma unroll
            for (int t = 0; t < LL; ++t) {
                unsigned mx = umax_(kB[t], key);
                key = umin_(kB[t], key);
                kB[t] = mx;
            }
        }
    }

    // park (upper half) then merge (lower half) -> exact top-12 per (row, list)
    unsigned* slotA = keysL + c*KP        + (wsub*4 + quad)*LL;
    unsigned* slotB = keysL + (16 + c)*KP + (wsub*4 + quad)*LL;
    if (half) {
        uint4* kd0 = (uint4*)slotA;
        kd0[0] = make_uint4(kA[0], kA[1], kA[2],  kA[3]);
        kd0[1] = make_uint4(kA[4], kA[5], kA[6],  kA[7]);
        kd0[2] = make_uint4(kA[8], kA[9], kA[10], kA[11]);
        uint4* kd1 = (uint4*)slotB;
        kd1[0] = make_uint4(kB[0], kB[1], kB[2],  kB[3]);
        kd1[1] = make_uint4(kB[4], kB[5], kB[6],  kB[7]);
        kd1[2] = make_uint4(kB[8], kB[9], kB[10], kB[11]);
    }
    __syncthreads();
    if (!half) {
        merge_top12(kA, slotA);
        merge_top12(kB, slotB);
    }
    __syncthreads();

    // ================= refine (quarter-wave per row; all 32 rows in one pass) ========
    int r = tid >> 4, g = tid & 15;
    int row = r;                             // 0..31

    // pass 1: stage 1+2 -> gselS; after this keysL is dead
    {
        unsigned mk[LL];
        {
            const uint4* ks = (const uint4*)(keysL + row*KP + g*LL);
            uint4 k0 = ks[0], k1 = ks[1], k2 = ks[2];
            mk[0]=k0.x; mk[1]=k0.y; mk[2]=k0.z;  mk[3]=k0.w;
            mk[4]=k1.x; mk[5]=k1.y; mk[6]=k1.z;  mk[7]=k1.w;
            mk[8]=k2.x; mk[9]=k2.y; mk[10]=k2.z; mk[11]=k2.w;
        }
        #pragma unroll 1
        for (int it = 0; it < EXTRG; ++it) {
            unsigned vm = rowmax16(mk[0]);
            bool win = (mk[0] == vm);
            #pragma unroll
            for (int q = 0; q < LL-1; ++q) mk[q] = win ? mk[q+1] : mk[q];
            mk[LL-1] = win ? 0u : mk[LL-1];
            if (g == (it & 15)) gselS[row*EXTRG + it] = vm;
        }
    }
    __syncthreads();   // keysL reads done -> aliased scratch may now be written

    // pass 2: stages 3..6
    {
        int n = n0 + row;
        uint2 anb = *(const uint2*)(xbf + (brow + n) * 64 + 4*g);
        float an0 = bflo(anb.x), an1 = bfhi(anb.x),
              an2 = bflo(anb.y), an3 = bfhi(anb.y);

        // stage 3: bf16 cooperative rescore of 96 candidates
        unsigned myk[6];
        #pragma unroll
        for (int j = 0; j < 6; ++j) {
            uint4 Gj = *(const uint4*)(gselS + row*EXTRG + 4*j);
            unsigned gk4[4] = {Gj.x, Gj.y, Gj.z, Gj.w};
            #pragma unroll
            for (int h = 0; h < 2; ++h) {
                uint2 vbs[8]; float xxm[8];
                #pragma unroll
                for (int u = 0; u < 8; ++u) {
                    int t = h*8 + u;
                    int m = (int)((gk4[t >> 2] & 1023u) << 2) | (t & 3);
                    vbs[u] = *(const uint2*)(xbf + (brow + m) * 64 + 4*g);
                    xxm[u] = xxc[brow + m];
                }
                #pragma unroll
                for (int u = 0; u < 8; ++u) {
                    int t = h*8 + u;
                    float p = an0 * bflo(vbs[u].x);
                    p = fmaf(an1, bfhi(vbs[u].x), p);
                    p = fmaf(an2, bflo(vbs[u].y), p);
                    p = fmaf(an3, bfhi(vbs[u].y), p);
                    p = rowsum16(p);
                    float sc = p + xxm[u];   // xxc is half-bias: == old sc/2 bit-exact
                    unsigned key = (__float_as_uint(sc) & 0xFFFFFF80u) | (unsigned)(j*16 + t);
                    if (t == g) myk[j] = key;
                }
            }
        }
        #pragma unroll
        for (int a = 1; a < 6; ++a)
            #pragma unroll
            for (int q = a; q > 0; --q) {
                unsigned lo = umin_(myk[q-1], myk[q]);
                myk[q-1] = umax_(myk[q-1], myk[q]);
                myk[q] = lo;
            }

        // stage 3.5: pop-shift merge -> exact top-NF of the 96 fp32 keys
        #pragma unroll 1
        for (int it = 0; it < NF; ++it) {
            unsigned vm = rowmax16(myk[0]);
            bool win = (myk[0] == vm);
            #pragma unroll
            for (int q = 0; q < 5; ++q) myk[q] = win ? myk[q+1] : myk[q];
            myk[5] = win ? 0u : myk[5];
            if (g == (it & 15)) {
                int i = (int)(vm & 127u);
                unsigned gk = gselS[row*EXTRG + (i >> 2)];
                m26S[row*NF + it] = (int)((gk & 1023u) << 2) | (i & 3);
            }
        }

        // stage 4: fp64 per-lane full dots (lane = candidate)
        #pragma unroll
        for (int round = 0; round < 2; ++round) {
            int t = round*16 + g;
            if (t < NF) {
                int m = m26S[row*NF + t];
                const float4* xm = (const float4*)(xt + (brow + m) * 64);
                const float4* xn = (const float4*)(xt + (brow + n) * 64);
                double acc0 = 0.0, acc1 = 0.0;
                #pragma unroll
                for (int i = 0; i < 8; ++i) {
                    float4 v0 = xm[2*i], a0 = xn[2*i];
                    float4 v1 = xm[2*i+1], a1 = xn[2*i+1];
                    acc0 += (double)a0.x*(double)v0.x + (double)a0.y*(double)v0.y
                          + (double)a0.z*(double)v0.z + (double)a0.w*(double)v0.w;
                    acc1 += (double)a1.x*(double)v1.x + (double)a1.y*(double)v1.y
                          + (double)a1.z*(double)v1.z + (double)a1.w*(double)v1.w;
                }
                d26S[row*NF + t] = 2.0*(acc0 + acc1) - xxd[brow + m];
            }
        }

        // stage 5: exact top-20 set by rank counting
        #pragma unroll
        for (int round = 0; round < 2; ++round) {
            int t = round*16 + g;
            if (t < NF) {
                double st = d26S[row*NF + t];
                int cnt = 0;
                #pragma unroll
                for (int p = 0; p < NF; ++p) cnt += (d26S[row*NF + p] > st) ? 1 : 0;
                if (cnt < KK) selS[row*KK + cnt] = m26S[row*NF + t];
            }
        }

        // stage 6: gather y (bf16), min/max per o, epilogue -> outS (aliased)
        float mn[4] = { __builtin_inff(), __builtin_inff(), __builtin_inff(), __builtin_inff() };
        float mx[4] = { -__builtin_inff(), -__builtin_inff(), -__builtin_inff(), -__builtin_inff() };
        #pragma unroll
        for (int hb = 0; hb < 2; ++hb) {
            uint2 yb[10];
            #pragma unroll
            for (int k = 0; k < 10; ++k)
                yb[k] = *(const uint2*)(ybf + (brow + selS[row*KK + hb*10 + k]) * 64 + 4*g);
            #pragma unroll
            for (int k = 0; k < 10; ++k) {
                float y0 = bflo(yb[k].x), y1 = bfhi(yb[k].x),
                      y2 = bflo(yb[k].y), y3 = bfhi(yb[k].y);
                mn[0] = fminf(mn[0], y0); mx[0] = fmaxf(mx[0], y0);
                mn[1] = fminf(mn[1], y1); mx[1] = fmaxf(mx[1], y1);
                mn[2] = fminf(mn[2], y2); mx[2] = fmaxf(mx[2], y2);
                mn[3] = fminf(mn[3], y3); mx[3] = fmaxf(mx[3], y3);
            }
        }
        uint2 zb = *(const uint2*)(zbf + (brow + n) * 64 + 4*g);
        float zz[4] = {bflo(zb.x), bfhi(zb.x), bflo(zb.y), bfhi(zb.y)};
        #pragma unroll
        for (int j = 0; j < 4; ++j) {
            int o = 4*g + j;
            float inv  = gamma[o] / sqrtf(rvar[o] + 1e-5f);
            float bias = beta[o] - rmean[o] * inv;
            float ysel = (inv >= 0.f) ? mn[j] : mx[j];
            float h = (zz[j] - ysel) * inv + bias;
            outS[o*33 + row] = (h >= 0.f) ? h : 0.2f * h;
        }
    }
    __syncthreads();   // cross-wave: output transpose
    {
        int o = tid >> 3, q = tid & 7;       // 512 threads: one float4 each
        float* ob = outS + o*33;
        float4 v0 = make_float4(ob[4*q], ob[4*q + 1], ob[4*q + 2], ob[4*q + 3]);
        float* op = out + ((size_t)(b*64 + o) << 12) + n0;
        *(float4*)(op + 4*q) = v0;
    }
}

extern "C" void kernel_launch(void* const* d_in, const int* in_sizes, int n_in,
                              void* d_out, int out_size, void* d_ws, size_t ws_size,
                              hipStream_t stream) {
    const float* x     = (const float*)d_in[0];
    const float* W     = (const float*)d_in[1];
    const float* gamma = (const float*)d_in[2];
    const float* beta  = (const float*)d_in[3];
    const float* rmean = (const float*)d_in[4];
    const float* rvar  = (const float*)d_in[5];
    float* out = (float*)d_out;

    char* ws = (char*)d_ws;
    float*          xt  = (float*)          (ws);                          //  8 MB
    unsigned short* xbf = (unsigned short*) (ws + ((size_t) 8 << 20));     //  4 MB
    unsigned short* ybf = (unsigned short*) (ws + ((size_t)12 << 20));     //  4 MB
    unsigned short* zbf = (unsigned short*) (ws + ((size_t)16 << 20));     //  4 MB
    double*         xxd = (double*)         (ws + ((size_t)20 << 20));     // 256 KB
    float*          xxc = (float*)          (ws + ((size_t)20 << 20) + (512 << 10)); // 128 KB

    k_prep<<< 512, 512, 0, stream>>>(x, W, xt, xbf, ybf, zbf, xxd, xxc);
    k_main<<<1024, 512, 0, stream>>>(xbf, xt, xxd, xxc, ybf, zbf,
                                     gamma, beta, rmean, rvar, out);
}

// Round 11
// 227.834 us; speedup vs baseline: 1.0285x; 1.0057x over previous
//
#include <hip/hip_runtime.h>
#include <hip/hip_bf16.h>

// EdgeConv B=8,C=64,N=4096,OUT=64,K=20.
// h[b,o,n,k] = z[b,n,o] - y[b,idx_k,o];  out = leakyrelu((z - min/max_k y)*inv + bias)
//
// FINAL (R11 = R7-verbatim revert). Session evidence for why this is the floor:
//  - occupancy 40->70% variants (R3/R5/R9): neutral/worse (per-wave serial chains)
//  - VALU-issue cuts (R7 C-fold): counters moved, time didn't (latency-bound)
//  - deeper ILP (R2/R6/R8): 64-VGPR allocator wall -> scratch spill
//  - chunk-split + exact merge (R9): merge cost == savings
//  - cooperative single-kernel fusion (R10): invalid under harness graph capture
#define NN 4096
#define KK 20
#define LL 12        // per-thread sorted list of GROUP keys (group = 4 consecutive m)
#define KP 196       // keysL row pitch in dwords (192 keys + 4 pad)
#define EXTRG 24     // groups merged out before rescore (exact: bearing groups are top-<=20)
#define NF 24        // fp64-rescored finalists

typedef short bf16x8 __attribute__((ext_vector_type(8)));
typedef float f32x4  __attribute__((ext_vector_type(4)));

__device__ __forceinline__ unsigned umax_(unsigned a, unsigned b){ return a > b ? a : b; }
__device__ __forceinline__ unsigned umin_(unsigned a, unsigned b){ return a < b ? a : b; }

__device__ __forceinline__ unsigned bfbits(float f) {   // fp32 -> bf16 bits, RNE
    unsigned u = __float_as_uint(f);
    return (u + 0x7FFFu + ((u >> 16) & 1u)) >> 16;
}
__device__ __forceinline__ float bflo(unsigned u){ return __builtin_bit_cast(float, u << 16); }
__device__ __forceinline__ float bfhi(unsigned u){ return __builtin_bit_cast(float, u & 0xFFFF0000u); }

__device__ __forceinline__ uint4 packfrag_u(float4 lo, float4 hi) {
    return make_uint4(bfbits(lo.x) | (bfbits(lo.y) << 16),
                      bfbits(lo.z) | (bfbits(lo.w) << 16),
                      bfbits(hi.x) | (bfbits(hi.y) << 16),
                      bfbits(hi.z) | (bfbits(hi.w) << 16));
}

// ---- DPP cross-lane (row = 16 lanes; row_ror:n = 0x120+n) -------------------
template<int CTRL>
__device__ __forceinline__ int dpp_mov(int v) {
    return __builtin_amdgcn_update_dpp(0, v, CTRL, 0xF, 0xF, true);
}
template<int CTRL>
__device__ __forceinline__ float dpp_addf(float v) {
    return v + __builtin_bit_cast(float, dpp_mov<CTRL>(__builtin_bit_cast(int, v)));
}
template<int CTRL>
__device__ __forceinline__ unsigned dpp_maxu(unsigned v) {
    return umax_(v, (unsigned)dpp_mov<CTRL>((int)v));
}
__device__ __forceinline__ float rowsum16(float v) {
    v = dpp_addf<0x128>(v); v = dpp_addf<0x124>(v);
    v = dpp_addf<0x122>(v); v = dpp_addf<0x121>(v);
    return v;
}
__device__ __forceinline__ unsigned rowmax16(unsigned v) {
    v = dpp_maxu<0x128>(v); v = dpp_maxu<0x124>(v);
    v = dpp_maxu<0x122>(v); v = dpp_maxu<0x121>(v);
    return v;
}

// ---------------- Kernel 1 (fused prep): transpose + xx + bf16 + y/z MFMA ----------------
// 512 blocks x 512 threads (8 waves) = 2 blocks/CU, 16 waves/CU.
__global__ __launch_bounds__(512) void k_prep(
    const float* __restrict__ x, const float* __restrict__ W,
    float* __restrict__ xt, unsigned short* __restrict__ xbf,
    unsigned short* __restrict__ ybf, unsigned short* __restrict__ zbf,
    double* __restrict__ xxd, float* __restrict__ xxc)
{
    __shared__ __align__(16) float fS[64 * 65];   // fp32 transpose staging (pitch 65)
    __shared__ __align__(16) uint4 bS[64 * 9];    // bf16 rows (pitch 9 uint4)
    __shared__ __align__(16) uint4 WfS[1024];     // 16384 B W fragments
    __shared__ double dS[8 * 64];                 // fp64 partials
    int tid = threadIdx.x;
    int b   = blockIdx.x >> 6;
    int n0  = (blockIdx.x & 63) << 6;
    int r   = tid & 63, p = tid >> 6;             // p in 0..7 -> 8 channels each
    size_t brow = (size_t)b * NN;
    int n = n0 + r;

    {   // W fragments (x-independent) -> LDS; layout (o*16 + sel*4 + quad)
        const float4* W4 = (const float4*)W;      // W row = 32 float4
        #pragma unroll
        for (int i = 0; i < 2; ++i) {
            int idx = i*512 + tid;                // 0..1023
            int o = idx >> 4, sel = (idx >> 2) & 3, quad = idx & 3;
            float4 lo = W4[(size_t)o*32 + sel*8 + quad*2];
            float4 hi = W4[(size_t)o*32 + sel*8 + quad*2 + 1];
            WfS[idx] = packfrag_u(lo, hi);
        }
    }

    float v[8];
    double s = 0.0;
    #pragma unroll
    for (int i = 0; i < 8; ++i) {
        float t = x[((size_t)(b*64 + p*8 + i) << 12) + n];   // 256B coalesced across r
        v[i] = t;
        s += (double)t * (double)t;
    }
    dS[p*64 + r] = s;
    #pragma unroll
    for (int i = 0; i < 8; ++i) fS[r*65 + p*8 + i] = v[i];
    {
        unsigned pk[4];
        #pragma unroll
        for (int i = 0; i < 4; ++i)
            pk[i] = bfbits(v[2*i]) | (bfbits(v[2*i+1]) << 16);
        bS[r*9 + p] = make_uint4(pk[0], pk[1], pk[2], pk[3]);
    }
    __syncthreads();      // only barrier: fS/bS/WfS/dS all ready, read-only after

    if (tid < 64) {
        double xx = 0.0;
        #pragma unroll
        for (int q = 0; q < 8; ++q) xx += dS[q*64 + tid];
        xxd[brow + n0 + tid] = xx;
        // HALF-bias: Gram seeds MFMA C with this directly (score = old/2, exact
        // monotone); stage-3 rescore uses p + xxc == old sc/2 bit-exact. (R6-verified)
        xxc[brow + n0 + tid] = (1024.f - (float)xx) * 0.5f;
    }
    // coalesced fp32 xt store: 1024 float4, 2 per thread
    #pragma unroll
    for (int i = 0; i < 2; ++i) {
        int idx = i*512 + tid;                 // 0..1023
        int rr = idx >> 4, c4 = idx & 15;
        float4 o = make_float4(fS[rr*65 + 4*c4],     fS[rr*65 + 4*c4 + 1],
                               fS[rr*65 + 4*c4 + 2], fS[rr*65 + 4*c4 + 3]);
        *(float4*)(xt + (brow + n0 + rr)*64 + 4*c4) = o;
    }
    // coalesced bf16 store: 512 uint4, 1 per thread
    {
        int rr = tid >> 3, u = tid & 7;
        ((uint4*)xbf)[(brow + n0 + rr)*8 + u] = bS[rr*9 + u];
    }

    // ---- y/z MFMA: 8 waves; wave w -> row-tile (w&3), ot-half (w>>2) ----
    int w = tid >> 6, lane = tid & 63, quad = lane >> 4, c = lane & 15;
    int lrow = (w & 3)*16 + c;
    bf16x8 bb0 = __builtin_bit_cast(bf16x8, bS[lrow*9 + quad]);       // ch quad*8..+7
    bf16x8 bb1 = __builtin_bit_cast(bf16x8, bS[lrow*9 + 4 + quad]);   // ch 32+quad*8..+7
    int nw = n0 + lrow;
    #pragma unroll 1
    for (int oh = 0; oh < 2; ++oh) {
        int ot = (w >> 2)*2 + oh;
        const uint4* wf = WfS + (ot*16 + c)*16 + quad;
        bf16x8 w1a = __builtin_bit_cast(bf16x8, wf[0]);
        bf16x8 w1b = __builtin_bit_cast(bf16x8, wf[4]);
        bf16x8 w2a = __builtin_bit_cast(bf16x8, wf[8]);
        bf16x8 w2b = __builtin_bit_cast(bf16x8, wf[12]);
        f32x4 acc1 = __builtin_amdgcn_mfma_f32_16x16x32_bf16(
            w1a, bb0, (f32x4){0.f,0.f,0.f,0.f}, 0, 0, 0);
        acc1 = __builtin_amdgcn_mfma_f32_16x16x32_bf16(w1b, bb1, acc1, 0, 0, 0);
        f32x4 acc2 = __builtin_amdgcn_mfma_f32_16x16x32_bf16(
            w2a, bb0, (f32x4){0.f,0.f,0.f,0.f}, 0, 0, 0);
        acc2 = __builtin_amdgcn_mfma_f32_16x16x32_bf16(w2b, bb1, acc2, 0, 0, 0);
        // thread (quad,c): o = ot*16 + quad*4 + j, n = nw; y=acc1, z=acc1+acc2
        float z0 = acc1[0]+acc2[0], z1 = acc1[1]+acc2[1],
              z2 = acc1[2]+acc2[2], z3 = acc1[3]+acc2[3];
        size_t obase = (brow + nw) * 64 + (ot*16 + quad*4);
        *(uint2*)(ybf + obase) = make_uint2(
            bfbits(acc1[0]) | (bfbits(acc1[1]) << 16),
            bfbits(acc1[2]) | (bfbits(acc1[3]) << 16));
        *(uint2*)(zbf + obase) = make_uint2(
            bfbits(z0) | (bfbits(z1) << 16),
            bfbits(z2) | (bfbits(z3) << 16));
    }
}

// ---------------- Kernel 2 (fused): 32-n tile Gram + top-12 keys + refine ----------------
// Best-verified body (R7): 32-row tile, two insert chains per wave, prefetch depth 2,
// xx-bias folded into MFMA C-operand, pass-2 scratch aliased into dead keysL.
// 56 VGPR, no spill, LDS 28160 B, 1024 blocks x 256 = 4 blocks/CU.
__global__ __launch_bounds__(256, 4) void k_main(
    const unsigned short* __restrict__ xbf, const float* __restrict__ xt,
    const double* __restrict__ xxd, const float* __restrict__ xxc,
    const unsigned short* __restrict__ ybf, const unsigned short* __restrict__ zbf,
    const float* __restrict__ gamma, const float* __restrict__ beta,
    const float* __restrict__ rmean, const float* __restrict__ rvar,
    float* __restrict__ out)
{
    __shared__ __align__(16) unsigned keysL[32 * KP];     // 25088 B (dead after pass 1)
    __shared__ __align__(16) unsigned gselS[32 * EXTRG];  // 3 KB
    // pass-2 scratch aliased into dead keysL (dword offsets; 5056 <= 6272 used):
    float*  outS = (float*)keysL;              // [0,2112)    64 o x pitch 33
    double* d26S = (double*)(keysL + 2112);    // [2112,3648) 32*NF doubles (byte 8448, 16B-aligned)
    int*    m26S = (int*)   (keysL + 3648);    // [3648,4416) 32*NF
    int*    selS = (int*)   (keysL + 4416);    // [4416,5056) 32*KK

    int tid  = threadIdx.x;
    int w    = tid >> 6, lane = tid & 63;
    int quad = lane >> 4, c = lane & 15;
    int b  = blockIdx.x & 7;                 // batch <-> XCD affinity
    int n0 = (blockIdx.x >> 3) << 5;         // 32-n tile
    size_t brow = (size_t)b * NN;

    const uint4* xb = (const uint4*)xbf;     // one row = 8 uint4

    // B fragments for the two fixed n-tiles
    size_t nr0 = (brow + n0 + c) * 8 + quad;
    size_t nr1 = (brow + n0 + 16 + c) * 8 + quad;
    bf16x8 b00 = __builtin_bit_cast(bf16x8, xb[nr0]);
    bf16x8 b01 = __builtin_bit_cast(bf16x8, xb[nr0 + 4]);
    bf16x8 b10 = __builtin_bit_cast(bf16x8, xb[nr1]);
    bf16x8 b11 = __builtin_bit_cast(bf16x8, xb[nr1 + 4]);

    unsigned kA[LL], kB[LL];
    #pragma unroll
    for (int i = 0; i < LL; ++i) { kA[i] = 0u; kB[i] = 0u; }

    // A stream, prefetch depth 2
    size_t abase = (brow + 16*w + c) * 8 + quad;
    size_t xxb   = brow + 16*w + quad*4;
    uint4  a0p[2], a1p[2];
    float4 xxp[2];
    a0p[0] = xb[abase];       a1p[0] = xb[abase + 4];
    a0p[1] = xb[abase + 512]; a1p[1] = xb[abase + 516];
    xxp[0] = *(const float4*)(xxc + xxb);
    xxp[1] = *(const float4*)(xxc + xxb + 64);

    #pragma unroll 2
    for (int chunk = 0; chunk < 64; ++chunk) {
        int s = chunk & 1;                   // constant after unroll-2
        uint4 ca0 = a0p[s], ca1 = a1p[s];
        f32x4 cin = __builtin_bit_cast(f32x4, xxp[s]);   // C-init = (1024-xx_m)/2
        if (chunk < 62) {
            size_t nb = abase + (size_t)(chunk + 2) * 512;
            a0p[s] = xb[nb]; a1p[s] = xb[nb + 4];
            xxp[s] = *(const float4*)(xxc + xxb + (chunk + 2)*64);
        }
        // acc = x_m . x_n + (1024 - xx_m)/2  ==  (old score)/2, monotone
        f32x4 accA = __builtin_amdgcn_mfma_f32_16x16x32_bf16(
            __builtin_bit_cast(bf16x8, ca0), b00, cin, 0, 0, 0);
        accA = __builtin_amdgcn_mfma_f32_16x16x32_bf16(
            __builtin_bit_cast(bf16x8, ca1), b01, accA, 0, 0, 0);
        f32x4 accB = __builtin_amdgcn_mfma_f32_16x16x32_bf16(
            __builtin_bit_cast(bf16x8, ca0), b10, cin, 0, 0, 0);
        accB = __builtin_amdgcn_mfma_f32_16x16x32_bf16(
            __builtin_bit_cast(bf16x8, ca1), b11, accB, 0, 0, 0);

        unsigned gid = (unsigned)((chunk << 4) | (w << 2) | quad);
        {   // tile 0: n = n0+c
            float gm = fmaxf(fmaxf(accA[0], accA[1]), fmaxf(accA[2], accA[3]));
            unsigned key = (__float_as_uint(gm) & 0xFFFFFC00u) | gid;
            #pragma unroll
            for (int t = 0; t < LL; ++t) {
                unsigned mx = umax_(kA[t], key);
                key = umin_(kA[t], key);
                kA[t] = mx;
            }
        }
        {   // tile 1: n = n0+16+c  (independent CE chain - interleaves with tile 0)
            float gm = fmaxf(fmaxf(accB[0], accB[1]), fmaxf(accB[2], accB[3]));
            unsigned key = (__float_as_uint(gm) & 0xFFFFFC00u) | gid;
            #pragma unroll
            for (int t = 0; t < LL; ++t) {
                unsigned mx = umax_(kB[t], key);
                key = umin_(kB[t], key);
                kB[t] = mx;
            }
        }
    }

    // park lists: row = 16*tile + c, list id = 4w+quad
    {
        uint4* kd0 = (uint4*)(keysL + c*KP + (w*4 + quad)*LL);
        kd0[0] = make_uint4(kA[0], kA[1], kA[2],  kA[3]);
        kd0[1] = make_uint4(kA[4], kA[5], kA[6],  kA[7]);
        kd0[2] = make_uint4(kA[8], kA[9], kA[10], kA[11]);
        uint4* kd1 = (uint4*)(keysL + (16 + c)*KP + (w*4 + quad)*LL);
        kd1[0] = make_uint4(kB[0], kB[1], kB[2],  kB[3]);
        kd1[1] = make_uint4(kB[4], kB[5], kB[6],  kB[7]);
        kd1[2] = make_uint4(kB[8], kB[9], kB[10], kB[11]);
    }
    __syncthreads();

    // ================= refine (quarter-wave per row; 2 rows per thread-group) ========
    int r = tid >> 4, g = tid & 15;

    // pass 1: stage 1+2 for both rows -> gselS; after this keysL is dead
    #pragma unroll 1
    for (int rr = 0; rr < 2; ++rr) {
        int row = rr*16 + r;
        unsigned mk[LL];
        {
            const uint4* ks = (const uint4*)(keysL + row*KP + g*LL);
            uint4 k0 = ks[0], k1 = ks[1], k2 = ks[2];
            mk[0]=k0.x; mk[1]=k0.y; mk[2]=k0.z;  mk[3]=k0.w;
            mk[4]=k1.x; mk[5]=k1.y; mk[6]=k1.z;  mk[7]=k1.w;
            mk[8]=k2.x; mk[9]=k2.y; mk[10]=k2.z; mk[11]=k2.w;
        }
        #pragma unroll 1
        for (int it = 0; it < EXTRG; ++it) {
            unsigned vm = rowmax16(mk[0]);
            bool win = (mk[0] == vm);
            #pragma unroll
            for (int q = 0; q < LL-1; ++q) mk[q] = win ? mk[q+1] : mk[q];
            mk[LL-1] = win ? 0u : mk[LL-1];
            if (g == (it & 15)) gselS[row*EXTRG + it] = vm;
        }
    }
    __syncthreads();   // keysL reads done -> aliased scratch may now be written

    // pass 2: stages 3..6 per row
    #pragma unroll 1
    for (int rr = 0; rr < 2; ++rr) {
        int row = rr*16 + r;
        int n = n0 + row;
        uint2 anb = *(const uint2*)(xbf + (brow + n) * 64 + 4*g);
        float an0 = bflo(anb.x), an1 = bfhi(anb.x),
              an2 = bflo(anb.y), an3 = bfhi(anb.y);

        // stage 3: bf16 cooperative rescore of 96 candidates
        unsigned myk[6];
        #pragma unroll
        for (int j = 0; j < 6; ++j) {
            uint4 Gj = *(const uint4*)(gselS + row*EXTRG + 4*j);
            unsigned gk4[4] = {Gj.x, Gj.y, Gj.z, Gj.w};
            #pragma unroll
            for (int h = 0; h < 2; ++h) {
                uint2 vbs[8]; float xxm[8];
                #pragma unroll
                for (int u = 0; u < 8; ++u) {
                    int t = h*8 + u;
                    int m = (int)((gk4[t >> 2] & 1023u) << 2) | (t & 3);
                    vbs[u] = *(const uint2*)(xbf + (brow + m) * 64 + 4*g);
                    xxm[u] = xxc[brow + m];
                }
                #pragma unroll
                for (int u = 0; u < 8; ++u) {
                    int t = h*8 + u;
                    float p = an0 * bflo(vbs[u].x);
                    p = fmaf(an1, bfhi(vbs[u].x), p);
                    p = fmaf(an2, bflo(vbs[u].y), p);
                    p = fmaf(an3, bfhi(vbs[u].y), p);
                    p = rowsum16(p);
                    float sc = p + xxm[u];   // xxc is half-bias: == old sc/2 bit-exact
                    unsigned key = (__float_as_uint(sc) & 0xFFFFFF80u) | (unsigned)(j*16 + t);
                    if (t == g) myk[j] = key;
                }
            }
        }
        #pragma unroll
        for (int a = 1; a < 6; ++a)
            #pragma unroll
            for (int q = a; q > 0; --q) {
                unsigned lo = umin_(myk[q-1], myk[q]);
                myk[q-1] = umax_(myk[q-1], myk[q]);
                myk[q] = lo;
            }

        // stage 3.5: pop-shift merge -> exact top-NF of the 96 fp32 keys
        #pragma unroll 1
        for (int it = 0; it < NF; ++it) {
            unsigned vm = rowmax16(myk[0]);
            bool win = (myk[0] == vm);
            #pragma unroll
            for (int q = 0; q < 5; ++q) myk[q] = win ? myk[q+1] : myk[q];
            myk[5] = win ? 0u : myk[5];
            if (g == (it & 15)) {
                int i = (int)(vm & 127u);
                unsigned gk = gselS[row*EXTRG + (i >> 2)];
                m26S[row*NF + it] = (int)((gk & 1023u) << 2) | (i & 3);
            }
        }

        // stage 4: fp64 per-lane full dots (lane = candidate)
        #pragma unroll
        for (int round = 0; round < 2; ++round) {
            int t = round*16 + g;
            if (t < NF) {
                int m = m26S[row*NF + t];
                const float4* xm = (const float4*)(xt + (brow + m) * 64);
                const float4* xn = (const float4*)(xt + (brow + n) * 64);
                double acc0 = 0.0, acc1 = 0.0;
                #pragma unroll
                for (int i = 0; i < 8; ++i) {
                    float4 v0 = xm[2*i], a0 = xn[2*i];
                    float4 v1 = xm[2*i+1], a1 = xn[2*i+1];
                    acc0 += (double)a0.x*(double)v0.x + (double)a0.y*(double)v0.y
                          + (double)a0.z*(double)v0.z + (double)a0.w*(double)v0.w;
                    acc1 += (double)a1.x*(double)v1.x + (double)a1.y*(double)v1.y
                          + (double)a1.z*(double)v1.z + (double)a1.w*(double)v1.w;
                }
                d26S[row*NF + t] = 2.0*(acc0 + acc1) - xxd[brow + m];
            }
        }

        // stage 5: exact top-20 set by rank counting
        #pragma unroll
        for (int round = 0; round < 2; ++round) {
            int t = round*16 + g;
            if (t < NF) {
                double st = d26S[row*NF + t];
                int cnt = 0;
                #pragma unroll
                for (int p = 0; p < NF; ++p) cnt += (d26S[row*NF + p] > st) ? 1 : 0;
                if (cnt < KK) selS[row*KK + cnt] = m26S[row*NF + t];
            }
        }

        // stage 6: gather y (bf16), min/max per o, epilogue -> outS (aliased)
        float mn[4] = { __builtin_inff(), __builtin_inff(), __builtin_inff(), __builtin_inff() };
        float mx[4] = { -__builtin_inff(), -__builtin_inff(), -__builtin_inff(), -__builtin_inff() };
        #pragma unroll
        for (int hb = 0; hb < 2; ++hb) {
            uint2 yb[10];
            #pragma unroll
            for (int k = 0; k < 10; ++k)
                yb[k] = *(const uint2*)(ybf + (brow + selS[row*KK + hb*10 + k]) * 64 + 4*g);
            #pragma unroll
            for (int k = 0; k < 10; ++k) {
                float y0 = bflo(yb[k].x), y1 = bfhi(yb[k].x),
                      y2 = bflo(yb[k].y), y3 = bfhi(yb[k].y);
                mn[0] = fminf(mn[0], y0); mx[0] = fmaxf(mx[0], y0);
                mn[1] = fminf(mn[1], y1); mx[1] = fmaxf(mx[1], y1);
                mn[2] = fminf(mn[2], y2); mx[2] = fmaxf(mx[2], y2);
                mn[3] = fminf(mn[3], y3); mx[3] = fmaxf(mx[3], y3);
            }
        }
        uint2 zb = *(const uint2*)(zbf + (brow + n) * 64 + 4*g);
        float zz[4] = {bflo(zb.x), bfhi(zb.x), bflo(zb.y), bfhi(zb.y)};
        #pragma unroll
        for (int j = 0; j < 4; ++j) {
            int o = 4*g + j;
            float inv  = gamma[o] / sqrtf(rvar[o] + 1e-5f);
            float bias = beta[o] - rmean[o] * inv;
            float ysel = (inv >= 0.f) ? mn[j] : mx[j];
            float h = (zz[j] - ysel) * inv + bias;
            outS[o*33 + row] = (h >= 0.f) ? h : 0.2f * h;
        }
    }
    __syncthreads();   // cross-wave: output transpose
    {
        int o = tid >> 2, q = tid & 3;
        float* ob = outS + o*33;
        float4 v0 = make_float4(ob[4*q],      ob[4*q + 1],  ob[4*q + 2],  ob[4*q + 3]);
        float4 v1 = make_float4(ob[16 + 4*q], ob[17 + 4*q], ob[18 + 4*q], ob[19 + 4*q]);
        float* op = out + ((size_t)(b*64 + o) << 12) + n0;
        *(float4*)(op + 4*q)      = v0;
        *(float4*)(op + 16 + 4*q) = v1;
    }
}

extern "C" void kernel_launch(void* const* d_in, const int* in_sizes, int n_in,
                              void* d_out, int out_size, void* d_ws, size_t ws_size,
                              hipStream_t stream) {
    const float* x     = (const float*)d_in[0];
    const float* W     = (const float*)d_in[1];
    const float* gamma = (const float*)d_in[2];
    const float* beta  = (const float*)d_in[3];
    const float* rmean = (const float*)d_in[4];
    const float* rvar  = (const float*)d_in[5];
    float* out = (float*)d_out;

    char* ws = (char*)d_ws;
    float*          xt  = (float*)          (ws);                          //  8 MB
    unsigned short* xbf = (unsigned short*) (ws + ((size_t) 8 << 20));     //  4 MB
    unsigned short* ybf = (unsigned short*) (ws + ((size_t)12 << 20));     //  4 MB
    unsigned short* zbf = (unsigned short*) (ws + ((size_t)16 << 20));     //  4 MB
    double*         xxd = (double*)         (ws + ((size_t)20 << 20));     // 256 KB
    float*          xxc = (float*)          (ws + ((size_t)20 << 20) + (512 << 10)); // 128 KB

    k_prep<<< 512, 512, 0, stream>>>(x, W, xt, xbf, ybf, zbf, xxd, xxc);
    k_main<<<1024, 256, 0, stream>>>(xbf, xt, xxd, xxc, ybf, zbf,
                                     gamma, beta, rmean, rvar, out);
}